// Round 12
// baseline (759.077 us; speedup 1.0000x reference)
//
#include <hip/hip_runtime.h>
#include <cstdint>
#include <cstddef>

typedef unsigned short u16;
typedef unsigned int   u32;
typedef short bf16x8 __attribute__((ext_vector_type(8)));
typedef float f32x4  __attribute__((ext_vector_type(4)));
typedef u16   u16x8  __attribute__((ext_vector_type(8)));
typedef u16   u16x4  __attribute__((ext_vector_type(4)));
typedef u16   u16x2  __attribute__((ext_vector_type(2)));

constexpr int B_  = 4;
constexpr int M_  = 1024;
constexpr int S_  = 1024;
constexpr int D_  = 1024;
constexpr int H_  = 16;
constexpr int FF_ = 4096;
constexpr int NE_ = 128;

__device__ __forceinline__ u16 f2bf(float f) {
    u32 u = __builtin_bit_cast(u32, f);
    u = (u + 0x7fffu + ((u >> 16) & 1u)) >> 16;   // RNE
    return (u16)u;
}
__device__ __forceinline__ float bf2f(u16 u) {
    u32 x = ((u32)u) << 16;
    return __builtin_bit_cast(float, x);
}
__device__ __forceinline__ void gload_lds16(const u16* g, u16* l) {
    __builtin_amdgcn_global_load_lds(
        (const __attribute__((address_space(1))) u32*)g,
        (__attribute__((address_space(3))) u32*)l, 16, 0, 0);
}

// ---------------------------------------------------------------------------
// Occupancy-first bf16 MFMA GEMM (64x128 tile), double-buffered LDS with ONE
// barrier per K-step (BK=32): issue next tile's gload_lds BEFORE computing
// the current tile; __syncthreads()'s implicit vmcnt(0) drain overlaps the
// MFMA work instead of preceding it. LDS 2x12=24 KB, VGPR ~100 -> ~5
// blocks/CU (unchanged from R10/R11).
// C[r][c] = sum_k A[r][k]*W[c][k] (+bias[c]).
// Chunk swizzle: q_phys = q ^ ((row>>1)&3) via pre-swizzled global source
// (linear gload_lds dest, rule #21) -> 2-way (free) ds_read_b128 banks.
// z-batched via sA/sW/sC element strides (also split-K partials).
// Optional fused transpose HT (requires OUT_BF16=1). K % 32 == 0.
// ---------------------------------------------------------------------------
template<int OUT_BF16, int RELU, int HAS_BIAS, int WRITE_HT>
__global__ __launch_bounds__(256) void gemm64_mfma(
    const u16* __restrict__ A, const u16* __restrict__ W,
    const float* __restrict__ bias, void* __restrict__ Cout,
    u16* __restrict__ HT,
    int K, int N, int lda, int ldw,
    size_t sA, size_t sW, size_t sC)
{
    __shared__ u16 As[2][64 * 32];     // 8 KB
    __shared__ u16 Bs[2][128 * 32];    // 16 KB
    const int tid = threadIdx.x;
    const int w = tid >> 6, l = tid & 63;
    const int fr = l & 15, g = l >> 4;
    const int bm = blockIdx.y * 64, bn = blockIdx.x * 128;
    const u16* Ab = A + (size_t)blockIdx.z * sA;
    const u16* Wb = W + (size_t)blockIdx.z * sW;

    const int qcol = ((l & 3) ^ ((l >> 3) & 3)) * 8;
    const int srow = w * 16 + (l >> 2);
    const u16* aG  = Ab + (size_t)(bm + srow) * lda + qcol;
    const u16* bG0 = Wb + (size_t)(bn + srow) * ldw + qcol;
    const u16* bG1 = bG0 + (size_t)64 * ldw;
    const int wo = w * 512;

    const int qsw = (g ^ ((fr >> 1) & 3)) * 8;

    f32x4 acc[4][2];
#pragma unroll
    for (int m = 0; m < 4; ++m)
#pragma unroll
        for (int n = 0; n < 2; ++n)
#pragma unroll
            for (int q = 0; q < 4; ++q) acc[m][n][q] = 0.f;

    const int nt = K >> 5;
    // prologue: stage tile 0 into buffer 0
    gload_lds16(aG,  &As[0][wo]);
    gload_lds16(bG0, &Bs[0][wo]);
    gload_lds16(bG1, &Bs[0][2048 + wo]);
    aG += 32; bG0 += 32; bG1 += 32;
    __syncthreads();                              // tile 0 landed

    for (int t = 0; t < nt; ++t) {
        const int cur = t & 1;
        if (t + 1 < nt) {                         // prefetch tile t+1
            const int nxt = cur ^ 1;
            gload_lds16(aG,  &As[nxt][wo]);
            gload_lds16(bG0, &Bs[nxt][wo]);
            gload_lds16(bG1, &Bs[nxt][2048 + wo]);
            aG += 32; bG0 += 32; bG1 += 32;
        }
        bf16x8 af[4], bf[2];
#pragma unroll
        for (int m = 0; m < 4; ++m)
            af[m] = *(const bf16x8*)&As[cur][(m * 16 + fr) * 32 + qsw];
#pragma unroll
        for (int n = 0; n < 2; ++n)
            bf[n] = *(const bf16x8*)&Bs[cur][(w * 32 + n * 16 + fr) * 32 + qsw];
#pragma unroll
        for (int m = 0; m < 4; ++m)
#pragma unroll
            for (int n = 0; n < 2; ++n)
                acc[m][n] = __builtin_amdgcn_mfma_f32_16x16x32_bf16(
                    af[m], bf[n], acc[m][n], 0, 0, 0);
        __syncthreads();                          // drain (overlapped) + sync
    }

    const int row0 = bm + g * 4;
#pragma unroll
    for (int n = 0; n < 2; ++n) {
        const int col = bn + w * 32 + n * 16 + fr;
        float bv = 0.f;
        if (HAS_BIAS) bv = bias[col];
#pragma unroll
        for (int m = 0; m < 4; ++m) {
            const int rowm = row0 + m * 16;
            u16 o[4];
#pragma unroll
            for (int j = 0; j < 4; ++j) {
                float v = acc[m][n][j] + bv;
                if (RELU) v = fmaxf(v, 0.f);
                const size_t idx = (size_t)blockIdx.z * sC +
                                   (size_t)(rowm + j) * N + col;
                if (OUT_BF16) { o[j] = f2bf(v); ((u16*)Cout)[idx] = o[j]; }
                else          { ((float*)Cout)[idx] = v; }
            }
            if (WRITE_HT) {
                u16x4 pk; pk[0] = o[0]; pk[1] = o[1]; pk[2] = o[2]; pk[3] = o[3];
                *(u16x4*)&HT[(((size_t)(rowm >> 10)) * N + col) * 1024 + (rowm & 1023)] = pk;
            }
        }
    }
}

// ---------------------------------------------------------------------------
// Flash attention fwd v3: QBLK=128, 512 thr = 8 waves sharing one K/V tile.
// Double-buffered LDS, reg-staged K/V (T14), direct Q frags, defer-max (T13).
// (R11-proven.)
// ---------------------------------------------------------------------------
__global__ __launch_bounds__(512) void flash_attn_kernel(
    const u16* __restrict__ Q, int qs,
    const u16* __restrict__ K, int ks,
    const u16* __restrict__ V, int vs,
    u16* __restrict__ O, int Slen)
{
    __shared__ u16 Ks[2][64][72];
    __shared__ u16 Vt[2][64][72];
    __shared__ u16 Pw[8][16][72];
    const int b = blockIdx.z, hh = blockIdx.y;
    const int m0 = blockIdx.x * 128;
    const int tid = threadIdx.x;
    const int w = tid >> 6, l = tid & 63;
    const int lq = l & 15, g = l >> 4;

    bf16x8 qf[2];
    {
        const u16* qp = Q + ((size_t)b * M_ + m0 + w * 16 + lq) * qs + hh * 64;
        u16x8 v0 = *(const u16x8*)(qp + g * 8);
        u16x8 v1 = *(const u16x8*)(qp + 32 + g * 8);
        u16x8 o0, o1;
#pragma unroll
        for (int i = 0; i < 8; ++i) {
            o0[i] = f2bf(bf2f(v0[i]) * 0.125f);
            o1[i] = f2bf(bf2f(v1[i]) * 0.125f);
        }
        qf[0] = __builtin_bit_cast(bf16x8, o0);
        qf[1] = __builtin_bit_cast(bf16x8, o1);
    }

    f32x4 acc_o[4];
#pragma unroll
    for (int nb = 0; nb < 4; ++nb)
#pragma unroll
        for (int j = 0; j < 4; ++j) acc_o[nb][j] = 0.f;
    float m_run = -1e30f, l_run = 0.f;

    const int krow = tid >> 3, kcg = (tid & 7) * 8;
    const int kp = tid & 31, dg = (tid >> 5) & 7;
    const int vstage = (tid < 256);

    const int nt = Slen >> 6;
    u16x8 kv0, va, vb;

#define ATT_LOAD(T_)                                                          \
    {                                                                         \
        const u16* kpp = K + ((size_t)b * Slen + (T_) * 64 + krow) * ks + hh * 64 + kcg; \
        kv0 = *(const u16x8*)kpp;                                             \
        if (vstage) {                                                         \
            const u16* vp0 = V + ((size_t)b * Slen + (T_) * 64 + 2 * kp) * vs + hh * 64 + dg * 8; \
            va = *(const u16x8*)vp0;                                          \
            vb = *(const u16x8*)(vp0 + vs);                                   \
        }                                                                     \
    }
#define ATT_WRITE(BUF_)                                                       \
    {                                                                         \
        *(u16x8*)&Ks[BUF_][krow][kcg] = kv0;                                  \
        if (vstage) {                                                         \
            _Pragma("unroll") for (int i = 0; i < 8; ++i) {                   \
                u16x2 pk; pk[0] = va[i]; pk[1] = vb[i];                       \
                *(u16x2*)&Vt[BUF_][dg * 8 + i][2 * kp] = pk;                  \
            }                                                                 \
        }                                                                     \
    }

    ATT_LOAD(0)
    ATT_WRITE(0)
    __syncthreads();

    for (int t = 0; t < nt; ++t) {
        if (t + 1 < nt) ATT_LOAD(t + 1)
        const int cb = t & 1;

        f32x4 s4[4];
#pragma unroll
        for (int mb = 0; mb < 4; ++mb) {
            f32x4 z = {0.f, 0.f, 0.f, 0.f};
            bf16x8 a0 = *(const bf16x8*)&Ks[cb][mb * 16 + lq][g * 8];
            bf16x8 a1 = *(const bf16x8*)&Ks[cb][mb * 16 + lq][32 + g * 8];
            z = __builtin_amdgcn_mfma_f32_16x16x32_bf16(a0, qf[0], z, 0, 0, 0);
            z = __builtin_amdgcn_mfma_f32_16x16x32_bf16(a1, qf[1], z, 0, 0, 0);
            s4[mb] = z;
        }

        float pm = -1e30f;
#pragma unroll
        for (int mb = 0; mb < 4; ++mb)
#pragma unroll
            for (int j = 0; j < 4; ++j) pm = fmaxf(pm, s4[mb][j]);
        pm = fmaxf(pm, __shfl_xor(pm, 16));
        pm = fmaxf(pm, __shfl_xor(pm, 32));

        u16 pbf[4][4];
        float ls = 0.f;
        if (__all(pm - m_run <= 8.f)) {
#pragma unroll
            for (int mb = 0; mb < 4; ++mb)
#pragma unroll
                for (int j = 0; j < 4; ++j) {
                    float p = __expf(s4[mb][j] - m_run);
                    ls += p;
                    pbf[mb][j] = f2bf(p);
                }
            ls += __shfl_xor(ls, 16);
            ls += __shfl_xor(ls, 32);
            l_run += ls;
        } else {
            const float m_new = fmaxf(m_run, pm);
            const float alpha = __expf(m_run - m_new);
#pragma unroll
            for (int mb = 0; mb < 4; ++mb)
#pragma unroll
                for (int j = 0; j < 4; ++j) {
                    float p = __expf(s4[mb][j] - m_new);
                    ls += p;
                    pbf[mb][j] = f2bf(p);
                }
            ls += __shfl_xor(ls, 16);
            ls += __shfl_xor(ls, 32);
            l_run = l_run * alpha + ls;
            m_run = m_new;
            float al[4];
#pragma unroll
            for (int j = 0; j < 4; ++j) al[j] = __shfl(alpha, 4 * g + j);
#pragma unroll
            for (int nb = 0; nb < 4; ++nb)
#pragma unroll
                for (int j = 0; j < 4; ++j) acc_o[nb][j] *= al[j];
        }

#pragma unroll
        for (int mb = 0; mb < 4; ++mb) {
            u16x4 pk;
            pk[0] = pbf[mb][0]; pk[1] = pbf[mb][1];
            pk[2] = pbf[mb][2]; pk[3] = pbf[mb][3];
            *(u16x4*)&Pw[w][lq][mb * 16 + g * 4] = pk;
        }

#pragma unroll
        for (int kc = 0; kc < 2; ++kc) {
            bf16x8 pa = *(const bf16x8*)&Pw[w][lq][kc * 32 + g * 8];
#pragma unroll
            for (int nb = 0; nb < 4; ++nb) {
                bf16x8 bv = *(const bf16x8*)&Vt[cb][nb * 16 + lq][kc * 32 + g * 8];
                acc_o[nb] = __builtin_amdgcn_mfma_f32_16x16x32_bf16(pa, bv, acc_o[nb], 0, 0, 0);
            }
        }

        if (t + 1 < nt) ATT_WRITE((t + 1) & 1)
        __syncthreads();
    }
#undef ATT_LOAD
#undef ATT_WRITE

    float linv[4];
#pragma unroll
    for (int j = 0; j < 4; ++j) linv[j] = 1.f / __shfl(l_run, 4 * g + j);
#pragma unroll
    for (int nb = 0; nb < 4; ++nb)
#pragma unroll
        for (int j = 0; j < 4; ++j) {
            const size_t row = (size_t)b * M_ + m0 + w * 16 + 4 * g + j;
            O[row * D_ + hh * 64 + nb * 16 + lq] = f2bf(acc_o[nb][j] * linv[j]);
        }
}

// ---------------------------------------------------------------------------
// One-shot f32->bf16 for all 7 tensors + phi transpose (blocks 10240..10751).
// ---------------------------------------------------------------------------
__global__ __launch_bounds__(256) void cvt_multi_kernel(
    const float* __restrict__ s0, u16* __restrict__ d0,
    const float* __restrict__ s1, u16* __restrict__ d1,
    const float* __restrict__ s2, u16* __restrict__ d2,
    const float* __restrict__ s3, u16* __restrict__ d3,
    const float* __restrict__ s4, u16* __restrict__ d4,
    const float* __restrict__ s5, u16* __restrict__ d5,
    const float* __restrict__ s6, u16* __restrict__ d6,
    const float* __restrict__ phi, u16* __restrict__ phiT)
{
    __shared__ u16 t[32][33];
    int blk = blockIdx.x;
    if (blk >= 10240) {
        // transpose phi (4096 x 128) f32 -> phiT (128 x 4096) bf16
        const int b2 = blk - 10240;                 // 0..511
        const int c0 = (b2 & 3) * 32, r0 = (b2 >> 2) * 32;
        const int x = threadIdx.x & 31, y = threadIdx.x >> 5;
        for (int i = y; i < 32; i += 8)
            t[i][x] = f2bf(phi[(size_t)(r0 + i) * 128 + c0 + x]);
        __syncthreads();
        for (int i = y; i < 32; i += 8)
            phiT[(size_t)(c0 + i) * 4096 + r0 + x] = t[x][i];
        return;
    }
    const float* s; u16* d;
    if      (blk < 2048) { s = s0; d = d0; }
    else if (blk < 4096) { s = s1; d = d1; blk -= 2048; }
    else if (blk < 5632) { s = s2; d = d2; blk -= 4096; }
    else if (blk < 6144) { s = s3; d = d3; blk -= 5632; }
    else if (blk < 7680) { s = s4; d = d4; blk -= 6144; }
    else if (blk < 8192) { s = s5; d = d5; blk -= 7680; }
    else                 { s = s6; d = d6; blk -= 8192; }
    const size_t i = ((size_t)blk * 256 + threadIdx.x) * 8;
    float4 a = *(const float4*)(s + i);
    float4 b = *(const float4*)(s + i + 4);
    u16x8 o;
    o[0] = f2bf(a.x); o[1] = f2bf(a.y); o[2] = f2bf(a.z); o[3] = f2bf(a.w);
    o[4] = f2bf(b.x); o[5] = f2bf(b.y); o[6] = f2bf(b.z); o[7] = f2bf(b.w);
    *(u16x8*)(d + i) = o;
}

// ---------------------------------------------------------------------------
// y = LayerNorm(X + R). X: f32 or bf16 (template). R: bf16 (proj).
// OUT_F32: write f32 (final output) else bf16. Grid: B*M rows, 256 thr.
// ---------------------------------------------------------------------------
template<int X_BF16, int OUT_F32>
__global__ __launch_bounds__(256) void resid_ln_kernel(
    const void* __restrict__ X, const u16* __restrict__ Rb,
    const float* __restrict__ g, const float* __restrict__ bt,
    void* __restrict__ Yout)
{
    __shared__ float s1[4], s2[4];
    const size_t row = blockIdx.x;
    const int tid = threadIdx.x;
    float xv[4];
    if (X_BF16) {
        u16x4 x4 = *(const u16x4*)((const u16*)X + row * 1024 + tid * 4);
#pragma unroll
        for (int i = 0; i < 4; ++i) xv[i] = bf2f(x4[i]);
    } else {
        float4 x4 = *(const float4*)((const float*)X + row * 1024 + tid * 4);
        xv[0] = x4.x; xv[1] = x4.y; xv[2] = x4.z; xv[3] = x4.w;
    }
    u16x4 r4 = *(const u16x4*)(Rb + row * 1024 + tid * 4);
    float v[4];
#pragma unroll
    for (int i = 0; i < 4; ++i) v[i] = xv[i] + bf2f(r4[i]);
    float s = v[0] + v[1] + v[2] + v[3];
    float q = v[0] * v[0] + v[1] * v[1] + v[2] * v[2] + v[3] * v[3];
#pragma unroll
    for (int off = 32; off; off >>= 1) {
        s += __shfl_xor(s, off);
        q += __shfl_xor(q, off);
    }
    if ((tid & 63) == 0) { s1[tid >> 6] = s; s2[tid >> 6] = q; }
    __syncthreads();
    s = s1[0] + s1[1] + s1[2] + s1[3];
    q = s2[0] + s2[1] + s2[2] + s2[3];
    const float mu = s * (1.f / 1024.f);
    const float var = q * (1.f / 1024.f) - mu * mu;
    const float rinv = rsqrtf(var + 1e-5f);
    const float4 g4 = *(const float4*)(g + tid * 4);
    const float4 b4 = *(const float4*)(bt + tid * 4);
    float o[4];
    o[0] = (v[0] - mu) * rinv * g4.x + b4.x;
    o[1] = (v[1] - mu) * rinv * g4.y + b4.y;
    o[2] = (v[2] - mu) * rinv * g4.z + b4.z;
    o[3] = (v[3] - mu) * rinv * g4.w + b4.w;
    if (OUT_F32) {
        *(float4*)((float*)Yout + row * 1024 + tid * 4) = *(float4*)o;
    } else {
        u16x4 ob;
        ob[0] = f2bf(o[0]); ob[1] = f2bf(o[1]);
        ob[2] = f2bf(o[2]); ob[3] = f2bf(o[3]);
        *(u16x4*)((u16*)Yout + row * 1024 + tid * 4) = ob;
    }
}

// ---------------------------------------------------------------------------
// Fused MoE softmaxes over the split-K logits partials.
// blocks x < NE: dispatch softmax over m for expert n=x (bf16 transposed out).
// blocks x >= NE: combine softmax over 128 experts, 4 rows per block.
// Grid (NE + 256, B), 256 threads.
// ---------------------------------------------------------------------------
__global__ __launch_bounds__(256) void moe_softmax_kernel(
    const float* __restrict__ logitsP, u16* __restrict__ dispT,
    u16* __restrict__ comb)
{
    __shared__ float red[4];
    constexpr size_t CH = (size_t)B_ * M_ * NE_;
    const int b = blockIdx.y;
    const int tid = threadIdx.x;
    if ((int)blockIdx.x < NE_) {
        const int n = blockIdx.x;
        u16* O = dispT + ((size_t)b * NE_ + n) * M_;
        float v[4];
#pragma unroll
        for (int i = 0; i < 4; ++i) {
            const size_t idx = (size_t)(b * M_ + tid + 256 * i) * NE_ + n;
            v[i] = logitsP[idx] + logitsP[CH + idx] + logitsP[2 * CH + idx] + logitsP[3 * CH + idx];
        }
        float mx = fmaxf(fmaxf(v[0], v[1]), fmaxf(v[2], v[3]));
#pragma unroll
        for (int off = 32; off; off >>= 1) mx = fmaxf(mx, __shfl_xor(mx, off));
        if ((tid & 63) == 0) red[tid >> 6] = mx;
        __syncthreads();
        mx = fmaxf(fmaxf(red[0], red[1]), fmaxf(red[2], red[3]));
        __syncthreads();
        float e[4], s = 0.f;
#pragma unroll
        for (int i = 0; i < 4; ++i) { e[i] = __expf(v[i] - mx); s += e[i]; }
#pragma unroll
        for (int off = 32; off; off >>= 1) s += __shfl_xor(s, off);
        if ((tid & 63) == 0) red[tid >> 6] = s;
        __syncthreads();
        s = red[0] + red[1] + red[2] + red[3];
        const float inv = 1.f / s;
#pragma unroll
        for (int i = 0; i < 4; ++i) O[tid + 256 * i] = f2bf(e[i] * inv);
    } else {
        const int idx4 = blockIdx.x - NE_;            // 0..255
        const int m = idx4 * 4 + (tid >> 6);          // 4 rows/block (1/wave)
        const int lane = tid & 63;
        const size_t row = (size_t)b * M_ + m;
        const size_t i0 = row * NE_ + lane;
        const size_t i1 = i0 + 64;
        float a = logitsP[i0] + logitsP[CH + i0] + logitsP[2 * CH + i0] + logitsP[3 * CH + i0];
        float c = logitsP[i1] + logitsP[CH + i1] + logitsP[2 * CH + i1] + logitsP[3 * CH + i1];
        float mx = fmaxf(a, c);
#pragma unroll
        for (int off = 32; off; off >>= 1) mx = fmaxf(mx, __shfl_xor(mx, off));
        float e0 = __expf(a - mx), e1 = __expf(c - mx);
        float s = e0 + e1;
#pragma unroll
        for (int off = 32; off; off >>= 1) s += __shfl_xor(s, off);
        const float inv = 1.f / s;
        comb[row * NE_ + lane]      = f2bf(e0 * inv);
        comb[row * NE_ + lane + 64] = f2bf(e1 * inv);
    }
}

// ---------------------------------------------------------------------------
// Expert partials: part[c][b][n][d] = sum_{f in chunk c} slots[b][n][f]*w[n][f][d]
// Reads exp_w (2.15 GB) exactly once, float4-coalesced -> HBM-bound floor.
// ---------------------------------------------------------------------------
__global__ __launch_bounds__(256) void expert_partial_kernel(
    const float* __restrict__ slots, const float* __restrict__ exp_w,
    float* __restrict__ part)
{
    __shared__ float sl[4][512];
    const int n = blockIdx.x;
    const int c = blockIdx.y;
    const int f0 = c * 512;
    const int t = threadIdx.x;
    for (int i = t; i < 2048; i += 256) {
        const int b = i >> 9, f = i & 511;
        sl[b][f] = slots[((size_t)b * NE_ + n) * FF_ + f0 + f];
    }
    __syncthreads();
    const int d4 = t * 4;
    const float* wp = exp_w + ((size_t)n * FF_ + f0) * D_ + d4;
    f32x4 acc[4];
#pragma unroll
    for (int b = 0; b < 4; ++b)
#pragma unroll
        for (int j = 0; j < 4; ++j) acc[b][j] = 0.f;
#pragma unroll 4
    for (int f = 0; f < 512; ++f) {
        const float4 w4 = *(const float4*)wp;
        wp += D_;
#pragma unroll
        for (int b = 0; b < 4; ++b) {
            const float s = sl[b][f];
            acc[b][0] = fmaf(s, w4.x, acc[b][0]);
            acc[b][1] = fmaf(s, w4.y, acc[b][1]);
            acc[b][2] = fmaf(s, w4.z, acc[b][2]);
            acc[b][3] = fmaf(s, w4.w, acc[b][3]);
        }
    }
#pragma unroll
    for (int b = 0; b < 4; ++b)
        *(f32x4*)&part[(((size_t)c * 4 + b) * NE_ + n) * D_ + d4] = acc[b];
}

// ---------------------------------------------------------------------------
// Reduce 8 partials + exp_b, emit yT[b][d][n] bf16 (fused transpose).
// ---------------------------------------------------------------------------
__global__ __launch_bounds__(256) void reduce_yT_kernel(
    const float* __restrict__ part, const float* __restrict__ exp_b,
    u16* __restrict__ yT)
{
    __shared__ float tile[32][33];
    const int d0 = blockIdx.x * 32, n0 = blockIdx.y * 32, b = blockIdx.z;
    const int x = threadIdx.x & 31, y = threadIdx.x >> 5;
    for (int i = y; i < 32; i += 8) {
        const int n = n0 + i;
        float s = exp_b[(size_t)n * D_ + d0 + x];
#pragma unroll
        for (int c = 0; c < 8; ++c)
            s += part[(((size_t)c * 4 + b) * NE_ + n) * D_ + d0 + x];
        tile[i][x] = s;
    }
    __syncthreads();
    for (int i = y; i < 32; i += 8)
        yT[((size_t)b * D_ + d0 + i) * NE_ + n0 + x] = f2bf(tile[x][i]);
}

// ---------------------------------------------------------------------------
extern "C" void kernel_launch(void* const* d_in, const int* in_sizes, int n_in,
                              void* d_out, int out_size, void* d_ws, size_t ws_size,
                              hipStream_t stream)
{
    const float* tgt      = (const float*)d_in[0];
    const float* memry    = (const float*)d_in[1];
    const float* sa_in_w  = (const float*)d_in[2];
    const float* sa_in_b  = (const float*)d_in[3];
    const float* sa_out_w = (const float*)d_in[4];
    const float* sa_out_b = (const float*)d_in[5];
    const float* ca_in_w  = (const float*)d_in[6];
    const float* ca_in_b  = (const float*)d_in[7];
    const float* ca_out_w = (const float*)d_in[8];
    const float* ca_out_b = (const float*)d_in[9];
    const float* norm1_g  = (const float*)d_in[10];
    const float* norm1_b  = (const float*)d_in[11];
    const float* norm2_g  = (const float*)d_in[12];
    const float* norm2_b  = (const float*)d_in[13];
    const float* norm3_g  = (const float*)d_in[14];
    const float* norm3_b  = (const float*)d_in[15];
    const float* lin_w    = (const float*)d_in[16];
    const float* lin_b    = (const float*)d_in[17];
    const float* phi      = (const float*)d_in[18];
    const float* exp_w    = (const float*)d_in[19];
    const float* exp_b    = (const float*)d_in[20];

    float* ws = (float*)d_ws;
    u16*   qkv_bf  = (u16*)(ws);                 // [4096][3072] u16 (CA reuse)
    u16*   proj_bf = (u16*)(ws + 6291456);       // [4096][1024] u16
    float* logitsP = ws + 18874368;              // 4 x 524,288
    float* part    = ws + 20971520;              // 4,194,304
    u16*   h_bf    = (u16*)(ws + 25165824);      // [4096][4096]
    u16*   hT_bf   = (u16*)(ws + 33554432);      // [4][4096][1024]
    u16*   obuf_bf = (u16*)(ws + 41943040);      // [4096][1024]
    u16*   x1_bf   = (u16*)(ws + 44040192);
    u16*   x2_bf   = (u16*)(ws + 46137344);
    u16*   tgt_bf  = (u16*)(ws + 48234496);
    u16*   mem_bf  = (u16*)(ws + 50331648);
    u16*   dispT   = (u16*)(ws + 52428800);      // [4][128][1024]
    u16*   comb_bf = (u16*)(ws + 52690944);      // [4096][128]
    u16*   yT_bf   = (u16*)(ws + 52953088);      // [4][1024][128]
    float* slots   = ws + 53215232;              // 2,097,152
    u16*   w_sa_in = (u16*)(ws + 55312384);
    u16*   w_sa_out= (u16*)(ws + 56885248);
    u16*   w_ca_in = (u16*)(ws + 57409536);
    u16*   w_ca_out= (u16*)(ws + 58982400);
    u16*   w_lin   = (u16*)(ws + 59506688);
    u16*   phiT    = (u16*)(ws + 61603840);

    constexpr size_t CH = (size_t)B_ * M_ * NE_;

    // ---- bf16 conversions + phi transpose (single launch) ----
    cvt_multi_kernel<<<10752, 256, 0, stream>>>(
        tgt, tgt_bf, memry, mem_bf, sa_in_w, w_sa_in, sa_out_w, w_sa_out,
        ca_in_w, w_ca_in, ca_out_w, w_ca_out, lin_w, w_lin, phi, phiT);

    // ---- Self-attention ----
    gemm64_mfma<1, 0, 1, 0><<<dim3(24, 64, 1), 256, 0, stream>>>(
        tgt_bf, w_sa_in, sa_in_b, qkv_bf, nullptr, 1024, 3072, 1024, 1024, 0, 0, 0);
    flash_attn_kernel<<<dim3(8, 16, 4), 512, 0, stream>>>(
        qkv_bf, 3072, qkv_bf + 1024, 3072, qkv_bf + 2048, 3072, obuf_bf, S_);
    gemm64_mfma<1, 0, 1, 0><<<dim3(8, 64, 1), 256, 0, stream>>>(
        obuf_bf, w_sa_out, sa_out_b, proj_bf, nullptr, 1024, 1024, 1024, 1024, 0, 0, 0);
    resid_ln_kernel<0, 0><<<4096, 256, 0, stream>>>(tgt, proj_bf, norm1_g, norm1_b, x1_bf);

    // ---- Cross-attention ----
    u16* qca_bf = qkv_bf;
    u16* kvca_bf = qkv_bf + (size_t)4096 * 1024;
    gemm64_mfma<1, 0, 1, 0><<<dim3(8, 64, 1), 256, 0, stream>>>(
        x1_bf, w_ca_in, ca_in_b, qca_bf, nullptr, 1024, 1024, 1024, 1024, 0, 0, 0);
    gemm64_mfma<1, 0, 1, 0><<<dim3(16, 64, 1), 256, 0, stream>>>(
        mem_bf, w_ca_in + (size_t)1024 * 1024, ca_in_b + 1024,
        kvca_bf, nullptr, 1024, 2048, 1024, 1024, 0, 0, 0);
    flash_attn_kernel<<<dim3(8, 16, 4), 512, 0, stream>>>(
        qca_bf, 1024, kvca_bf, 2048, kvca_bf + 1024, 2048, obuf_bf, S_);
    gemm64_mfma<1, 0, 1, 0><<<dim3(8, 64, 1), 256, 0, stream>>>(
        obuf_bf, w_ca_out, ca_out_b, proj_bf, nullptr, 1024, 1024, 1024, 1024, 0, 0, 0);
    resid_ln_kernel<1, 0><<<4096, 256, 0, stream>>>(x1_bf, proj_bf, norm2_g, norm2_b, x2_bf);

    // ---- FF + SoftMoE ----
    gemm64_mfma<1, 1, 1, 1><<<dim3(32, 64, 1), 256, 0, stream>>>(
        x2_bf, w_lin, lin_b, h_bf, hT_bf, 1024, 4096, 1024, 1024, 0, 0, 0);
    // logits: split-K x4 (z = K-chunk of 1024)
    gemm64_mfma<0, 0, 0, 0><<<dim3(1, 64, 4), 256, 0, stream>>>(
        h_bf, phiT, nullptr, logitsP, nullptr, 1024, 128, 4096, 4096,
        1024, 1024, CH);
    moe_softmax_kernel<<<dim3(NE_ + 256, B_), 256, 0, stream>>>(logitsP, dispT, comb_bf);
    // slots = dispT @ hT (batched over B)
    gemm64_mfma<0, 0, 0, 0><<<dim3(32, 2, 4), 256, 0, stream>>>(
        dispT, hT_bf, nullptr, slots, nullptr, 1024, 4096, 1024, 1024,
        (size_t)NE_ * M_, (size_t)FF_ * M_, (size_t)NE_ * FF_);
    expert_partial_kernel<<<dim3(NE_, 8), 256, 0, stream>>>(slots, exp_w, part);
    reduce_yT_kernel<<<dim3(32, 4, 4), 256, 0, stream>>>(part, exp_b, yT_bf);
    // ff_out = combine @ y (batched over B), bf16 out
    gemm64_mfma<1, 0, 0, 0><<<dim3(8, 16, 4), 256, 0, stream>>>(
        comb_bf, yT_bf, nullptr, proj_bf, nullptr, 128, 1024, 128, 128,
        (size_t)M_ * NE_, (size_t)D_ * NE_, (size_t)M_ * D_);
    resid_ln_kernel<1, 1><<<4096, 256, 0, stream>>>(x2_bf, proj_bf, norm3_g, norm3_b,
                                                    (float*)d_out);
}

// Round 13
// 740.046 us; speedup vs baseline: 1.0257x; 1.0257x over previous
//
#include <hip/hip_runtime.h>
#include <cstdint>
#include <cstddef>

typedef unsigned short u16;
typedef unsigned int   u32;
typedef short bf16x8 __attribute__((ext_vector_type(8)));
typedef float f32x4  __attribute__((ext_vector_type(4)));
typedef u16   u16x8  __attribute__((ext_vector_type(8)));
typedef u16   u16x4  __attribute__((ext_vector_type(4)));
typedef u16   u16x2  __attribute__((ext_vector_type(2)));

constexpr int B_  = 4;
constexpr int M_  = 1024;
constexpr int S_  = 1024;
constexpr int D_  = 1024;
constexpr int H_  = 16;
constexpr int FF_ = 4096;
constexpr int NE_ = 128;

__device__ __forceinline__ u16 f2bf(float f) {
    u32 u = __builtin_bit_cast(u32, f);
    u = (u + 0x7fffu + ((u >> 16) & 1u)) >> 16;   // RNE
    return (u16)u;
}
__device__ __forceinline__ float bf2f(u16 u) {
    u32 x = ((u32)u) << 16;
    return __builtin_bit_cast(float, x);
}
__device__ __forceinline__ void gload_lds16(const u16* g, u16* l) {
    __builtin_amdgcn_global_load_lds(
        (const __attribute__((address_space(1))) u32*)g,
        (__attribute__((address_space(3))) u32*)l, 16, 0, 0);
}

// ---------------------------------------------------------------------------
// Occupancy-first bf16 MFMA GEMM (64x128 tile), K-step 64 = 2 BK=32 sub-tiles
// per barrier pair (R10/R11-proven best: K-step-32 dbuf regressed in R12
// because __syncthreads drains vmcnt(0) INCLUDING the just-issued prefetch).
// LDS 24 KB, VGPR ~100 -> ~5 blocks/CU.
// C[r][c] = sum_k A[r][k]*W[c][k] (+bias[c]).
// Chunk swizzle per sub-tile: q_phys = q ^ ((row>>1)&3) via pre-swizzled
// global source (linear gload_lds dest, rule #21) -> 2-way (free) banks.
// z-batched via sA/sW/sC element strides (also split-K partials).
// Optional fused transpose HT (requires OUT_BF16=1). K % 64 == 0.
// ---------------------------------------------------------------------------
template<int OUT_BF16, int RELU, int HAS_BIAS, int WRITE_HT>
__global__ __launch_bounds__(256) void gemm64_mfma(
    const u16* __restrict__ A, const u16* __restrict__ W,
    const float* __restrict__ bias, void* __restrict__ Cout,
    u16* __restrict__ HT,
    int K, int N, int lda, int ldw,
    size_t sA, size_t sW, size_t sC)
{
    __shared__ u16 As[2][64 * 32];     // 8 KB
    __shared__ u16 Bs[2][128 * 32];    // 16 KB
    const int tid = threadIdx.x;
    const int w = tid >> 6, l = tid & 63;
    const int fr = l & 15, g = l >> 4;
    const int bm = blockIdx.y * 64, bn = blockIdx.x * 128;
    const u16* Ab = A + (size_t)blockIdx.z * sA;
    const u16* Wb = W + (size_t)blockIdx.z * sW;

    const int qcol = ((l & 3) ^ ((l >> 3) & 3)) * 8;
    const int srow = w * 16 + (l >> 2);
    const u16* aG  = Ab + (size_t)(bm + srow) * lda + qcol;
    const u16* bG0 = Wb + (size_t)(bn + srow) * ldw + qcol;
    const u16* bG1 = bG0 + (size_t)64 * ldw;
    const int wo = w * 512;

    const int qsw = (g ^ ((fr >> 1) & 3)) * 8;

    f32x4 acc[4][2];
#pragma unroll
    for (int m = 0; m < 4; ++m)
#pragma unroll
        for (int n = 0; n < 2; ++n)
#pragma unroll
            for (int q = 0; q < 4; ++q) acc[m][n][q] = 0.f;

    for (int k0 = 0; k0 < K; k0 += 64) {
        __syncthreads();                    // prev reads done before overwrite
        gload_lds16(aG,       &As[0][wo]);
        gload_lds16(bG0,      &Bs[0][wo]);
        gload_lds16(bG1,      &Bs[0][2048 + wo]);
        gload_lds16(aG  + 32, &As[1][wo]);
        gload_lds16(bG0 + 32, &Bs[1][wo]);
        gload_lds16(bG1 + 32, &Bs[1][2048 + wo]);
        aG += 64; bG0 += 64; bG1 += 64;
        __syncthreads();                    // drains vmcnt(0): both tiles ready
#pragma unroll
        for (int h = 0; h < 2; ++h) {
            bf16x8 af[4], bf[2];
#pragma unroll
            for (int m = 0; m < 4; ++m)
                af[m] = *(const bf16x8*)&As[h][(m * 16 + fr) * 32 + qsw];
#pragma unroll
            for (int n = 0; n < 2; ++n)
                bf[n] = *(const bf16x8*)&Bs[h][(w * 32 + n * 16 + fr) * 32 + qsw];
#pragma unroll
            for (int m = 0; m < 4; ++m)
#pragma unroll
                for (int n = 0; n < 2; ++n)
                    acc[m][n] = __builtin_amdgcn_mfma_f32_16x16x32_bf16(
                        af[m], bf[n], acc[m][n], 0, 0, 0);
        }
    }

    const int row0 = bm + g * 4;
#pragma unroll
    for (int n = 0; n < 2; ++n) {
        const int col = bn + w * 32 + n * 16 + fr;
        float bv = 0.f;
        if (HAS_BIAS) bv = bias[col];
#pragma unroll
        for (int m = 0; m < 4; ++m) {
            const int rowm = row0 + m * 16;
            u16 o[4];
#pragma unroll
            for (int j = 0; j < 4; ++j) {
                float v = acc[m][n][j] + bv;
                if (RELU) v = fmaxf(v, 0.f);
                const size_t idx = (size_t)blockIdx.z * sC +
                                   (size_t)(rowm + j) * N + col;
                if (OUT_BF16) { o[j] = f2bf(v); ((u16*)Cout)[idx] = o[j]; }
                else          { ((float*)Cout)[idx] = v; }
            }
            if (WRITE_HT) {
                u16x4 pk; pk[0] = o[0]; pk[1] = o[1]; pk[2] = o[2]; pk[3] = o[3];
                *(u16x4*)&HT[(((size_t)(rowm >> 10)) * N + col) * 1024 + (rowm & 1023)] = pk;
            }
        }
    }
}

// ---------------------------------------------------------------------------
// Flash attention fwd v3: QBLK=128, 512 thr = 8 waves sharing one K/V tile.
// Double-buffered LDS, reg-staged K/V (T14), direct Q frags, defer-max (T13).
// (R11-proven.)
// ---------------------------------------------------------------------------
__global__ __launch_bounds__(512) void flash_attn_kernel(
    const u16* __restrict__ Q, int qs,
    const u16* __restrict__ K, int ks,
    const u16* __restrict__ V, int vs,
    u16* __restrict__ O, int Slen)
{
    __shared__ u16 Ks[2][64][72];
    __shared__ u16 Vt[2][64][72];
    __shared__ u16 Pw[8][16][72];
    const int b = blockIdx.z, hh = blockIdx.y;
    const int m0 = blockIdx.x * 128;
    const int tid = threadIdx.x;
    const int w = tid >> 6, l = tid & 63;
    const int lq = l & 15, g = l >> 4;

    bf16x8 qf[2];
    {
        const u16* qp = Q + ((size_t)b * M_ + m0 + w * 16 + lq) * qs + hh * 64;
        u16x8 v0 = *(const u16x8*)(qp + g * 8);
        u16x8 v1 = *(const u16x8*)(qp + 32 + g * 8);
        u16x8 o0, o1;
#pragma unroll
        for (int i = 0; i < 8; ++i) {
            o0[i] = f2bf(bf2f(v0[i]) * 0.125f);
            o1[i] = f2bf(bf2f(v1[i]) * 0.125f);
        }
        qf[0] = __builtin_bit_cast(bf16x8, o0);
        qf[1] = __builtin_bit_cast(bf16x8, o1);
    }

    f32x4 acc_o[4];
#pragma unroll
    for (int nb = 0; nb < 4; ++nb)
#pragma unroll
        for (int j = 0; j < 4; ++j) acc_o[nb][j] = 0.f;
    float m_run = -1e30f, l_run = 0.f;

    const int krow = tid >> 3, kcg = (tid & 7) * 8;
    const int kp = tid & 31, dg = (tid >> 5) & 7;
    const int vstage = (tid < 256);

    const int nt = Slen >> 6;
    u16x8 kv0, va, vb;

#define ATT_LOAD(T_)                                                          \
    {                                                                         \
        const u16* kpp = K + ((size_t)b * Slen + (T_) * 64 + krow) * ks + hh * 64 + kcg; \
        kv0 = *(const u16x8*)kpp;                                             \
        if (vstage) {                                                         \
            const u16* vp0 = V + ((size_t)b * Slen + (T_) * 64 + 2 * kp) * vs + hh * 64 + dg * 8; \
            va = *(const u16x8*)vp0;                                          \
            vb = *(const u16x8*)(vp0 + vs);                                   \
        }                                                                     \
    }
#define ATT_WRITE(BUF_)                                                       \
    {                                                                         \
        *(u16x8*)&Ks[BUF_][krow][kcg] = kv0;                                  \
        if (vstage) {                                                         \
            _Pragma("unroll") for (int i = 0; i < 8; ++i) {                   \
                u16x2 pk; pk[0] = va[i]; pk[1] = vb[i];                       \
                *(u16x2*)&Vt[BUF_][dg * 8 + i][2 * kp] = pk;                  \
            }                                                                 \
        }                                                                     \
    }

    ATT_LOAD(0)
    ATT_WRITE(0)
    __syncthreads();

    for (int t = 0; t < nt; ++t) {
        if (t + 1 < nt) ATT_LOAD(t + 1)
        const int cb = t & 1;

        f32x4 s4[4];
#pragma unroll
        for (int mb = 0; mb < 4; ++mb) {
            f32x4 z = {0.f, 0.f, 0.f, 0.f};
            bf16x8 a0 = *(const bf16x8*)&Ks[cb][mb * 16 + lq][g * 8];
            bf16x8 a1 = *(const bf16x8*)&Ks[cb][mb * 16 + lq][32 + g * 8];
            z = __builtin_amdgcn_mfma_f32_16x16x32_bf16(a0, qf[0], z, 0, 0, 0);
            z = __builtin_amdgcn_mfma_f32_16x16x32_bf16(a1, qf[1], z, 0, 0, 0);
            s4[mb] = z;
        }

        float pm = -1e30f;
#pragma unroll
        for (int mb = 0; mb < 4; ++mb)
#pragma unroll
            for (int j = 0; j < 4; ++j) pm = fmaxf(pm, s4[mb][j]);
        pm = fmaxf(pm, __shfl_xor(pm, 16));
        pm = fmaxf(pm, __shfl_xor(pm, 32));

        u16 pbf[4][4];
        float ls = 0.f;
        if (__all(pm - m_run <= 8.f)) {
#pragma unroll
            for (int mb = 0; mb < 4; ++mb)
#pragma unroll
                for (int j = 0; j < 4; ++j) {
                    float p = __expf(s4[mb][j] - m_run);
                    ls += p;
                    pbf[mb][j] = f2bf(p);
                }
            ls += __shfl_xor(ls, 16);
            ls += __shfl_xor(ls, 32);
            l_run += ls;
        } else {
            const float m_new = fmaxf(m_run, pm);
            const float alpha = __expf(m_run - m_new);
#pragma unroll
            for (int mb = 0; mb < 4; ++mb)
#pragma unroll
                for (int j = 0; j < 4; ++j) {
                    float p = __expf(s4[mb][j] - m_new);
                    ls += p;
                    pbf[mb][j] = f2bf(p);
                }
            ls += __shfl_xor(ls, 16);
            ls += __shfl_xor(ls, 32);
            l_run = l_run * alpha + ls;
            m_run = m_new;
            float al[4];
#pragma unroll
            for (int j = 0; j < 4; ++j) al[j] = __shfl(alpha, 4 * g + j);
#pragma unroll
            for (int nb = 0; nb < 4; ++nb)
#pragma unroll
                for (int j = 0; j < 4; ++j) acc_o[nb][j] *= al[j];
        }

#pragma unroll
        for (int mb = 0; mb < 4; ++mb) {
            u16x4 pk;
            pk[0] = pbf[mb][0]; pk[1] = pbf[mb][1];
            pk[2] = pbf[mb][2]; pk[3] = pbf[mb][3];
            *(u16x4*)&Pw[w][lq][mb * 16 + g * 4] = pk;
        }

#pragma unroll
        for (int kc = 0; kc < 2; ++kc) {
            bf16x8 pa = *(const bf16x8*)&Pw[w][lq][kc * 32 + g * 8];
#pragma unroll
            for (int nb = 0; nb < 4; ++nb) {
                bf16x8 bv = *(const bf16x8*)&Vt[cb][nb * 16 + lq][kc * 32 + g * 8];
                acc_o[nb] = __builtin_amdgcn_mfma_f32_16x16x32_bf16(pa, bv, acc_o[nb], 0, 0, 0);
            }
        }

        if (t + 1 < nt) ATT_WRITE((t + 1) & 1)
        __syncthreads();
    }
#undef ATT_LOAD
#undef ATT_WRITE

    float linv[4];
#pragma unroll
    for (int j = 0; j < 4; ++j) linv[j] = 1.f / __shfl(l_run, 4 * g + j);
#pragma unroll
    for (int nb = 0; nb < 4; ++nb)
#pragma unroll
        for (int j = 0; j < 4; ++j) {
            const size_t row = (size_t)b * M_ + m0 + w * 16 + 4 * g + j;
            O[row * D_ + hh * 64 + nb * 16 + lq] = f2bf(acc_o[nb][j] * linv[j]);
        }
}

// ---------------------------------------------------------------------------
// One-shot f32->bf16 for all 7 tensors + phi transpose (blocks 10240..10751).
// ---------------------------------------------------------------------------
__global__ __launch_bounds__(256) void cvt_multi_kernel(
    const float* __restrict__ s0, u16* __restrict__ d0,
    const float* __restrict__ s1, u16* __restrict__ d1,
    const float* __restrict__ s2, u16* __restrict__ d2,
    const float* __restrict__ s3, u16* __restrict__ d3,
    const float* __restrict__ s4, u16* __restrict__ d4,
    const float* __restrict__ s5, u16* __restrict__ d5,
    const float* __restrict__ s6, u16* __restrict__ d6,
    const float* __restrict__ phi, u16* __restrict__ phiT)
{
    __shared__ u16 t[32][33];
    int blk = blockIdx.x;
    if (blk >= 10240) {
        const int b2 = blk - 10240;                 // 0..511
        const int c0 = (b2 & 3) * 32, r0 = (b2 >> 2) * 32;
        const int x = threadIdx.x & 31, y = threadIdx.x >> 5;
        for (int i = y; i < 32; i += 8)
            t[i][x] = f2bf(phi[(size_t)(r0 + i) * 128 + c0 + x]);
        __syncthreads();
        for (int i = y; i < 32; i += 8)
            phiT[(size_t)(c0 + i) * 4096 + r0 + x] = t[x][i];
        return;
    }
    const float* s; u16* d;
    if      (blk < 2048) { s = s0; d = d0; }
    else if (blk < 4096) { s = s1; d = d1; blk -= 2048; }
    else if (blk < 5632) { s = s2; d = d2; blk -= 4096; }
    else if (blk < 6144) { s = s3; d = d3; blk -= 5632; }
    else if (blk < 7680) { s = s4; d = d4; blk -= 6144; }
    else if (blk < 8192) { s = s5; d = d5; blk -= 7680; }
    else                 { s = s6; d = d6; blk -= 8192; }
    const size_t i = ((size_t)blk * 256 + threadIdx.x) * 8;
    float4 a = *(const float4*)(s + i);
    float4 b = *(const float4*)(s + i + 4);
    u16x8 o;
    o[0] = f2bf(a.x); o[1] = f2bf(a.y); o[2] = f2bf(a.z); o[3] = f2bf(a.w);
    o[4] = f2bf(b.x); o[5] = f2bf(b.y); o[6] = f2bf(b.z); o[7] = f2bf(b.w);
    *(u16x8*)(d + i) = o;
}

// ---------------------------------------------------------------------------
// y = LayerNorm(X + R). X: f32 or bf16 (template). R: bf16 (proj).
// OUT_F32: write f32 (final output) else bf16. Grid: B*M rows, 256 thr.
// ---------------------------------------------------------------------------
template<int X_BF16, int OUT_F32>
__global__ __launch_bounds__(256) void resid_ln_kernel(
    const void* __restrict__ X, const u16* __restrict__ Rb,
    const float* __restrict__ g, const float* __restrict__ bt,
    void* __restrict__ Yout)
{
    __shared__ float s1[4], s2[4];
    const size_t row = blockIdx.x;
    const int tid = threadIdx.x;
    float xv[4];
    if (X_BF16) {
        u16x4 x4 = *(const u16x4*)((const u16*)X + row * 1024 + tid * 4);
#pragma unroll
        for (int i = 0; i < 4; ++i) xv[i] = bf2f(x4[i]);
    } else {
        float4 x4 = *(const float4*)((const float*)X + row * 1024 + tid * 4);
        xv[0] = x4.x; xv[1] = x4.y; xv[2] = x4.z; xv[3] = x4.w;
    }
    u16x4 r4 = *(const u16x4*)(Rb + row * 1024 + tid * 4);
    float v[4];
#pragma unroll
    for (int i = 0; i < 4; ++i) v[i] = xv[i] + bf2f(r4[i]);
    float s = v[0] + v[1] + v[2] + v[3];
    float q = v[0] * v[0] + v[1] * v[1] + v[2] * v[2] + v[3] * v[3];
#pragma unroll
    for (int off = 32; off; off >>= 1) {
        s += __shfl_xor(s, off);
        q += __shfl_xor(q, off);
    }
    if ((tid & 63) == 0) { s1[tid >> 6] = s; s2[tid >> 6] = q; }
    __syncthreads();
    s = s1[0] + s1[1] + s1[2] + s1[3];
    q = s2[0] + s2[1] + s2[2] + s2[3];
    const float mu = s * (1.f / 1024.f);
    const float var = q * (1.f / 1024.f) - mu * mu;
    const float rinv = rsqrtf(var + 1e-5f);
    const float4 g4 = *(const float4*)(g + tid * 4);
    const float4 b4 = *(const float4*)(bt + tid * 4);
    float o[4];
    o[0] = (v[0] - mu) * rinv * g4.x + b4.x;
    o[1] = (v[1] - mu) * rinv * g4.y + b4.y;
    o[2] = (v[2] - mu) * rinv * g4.z + b4.z;
    o[3] = (v[3] - mu) * rinv * g4.w + b4.w;
    if (OUT_F32) {
        *(float4*)((float*)Yout + row * 1024 + tid * 4) = *(float4*)o;
    } else {
        u16x4 ob;
        ob[0] = f2bf(o[0]); ob[1] = f2bf(o[1]);
        ob[2] = f2bf(o[2]); ob[3] = f2bf(o[3]);
        *(u16x4*)((u16*)Yout + row * 1024 + tid * 4) = ob;
    }
}

// ---------------------------------------------------------------------------
// Fused MoE softmaxes over the split-K logits partials.
// blocks x < NE: dispatch softmax over m for expert n=x (bf16 transposed out).
// blocks x >= NE: combine softmax over 128 experts, 4 rows per block.
// Grid (NE + 256, B), 256 threads.
// ---------------------------------------------------------------------------
__global__ __launch_bounds__(256) void moe_softmax_kernel(
    const float* __restrict__ logitsP, u16* __restrict__ dispT,
    u16* __restrict__ comb)
{
    __shared__ float red[4];
    constexpr size_t CH = (size_t)B_ * M_ * NE_;
    const int b = blockIdx.y;
    const int tid = threadIdx.x;
    if ((int)blockIdx.x < NE_) {
        const int n = blockIdx.x;
        u16* O = dispT + ((size_t)b * NE_ + n) * M_;
        float v[4];
#pragma unroll
        for (int i = 0; i < 4; ++i) {
            const size_t idx = (size_t)(b * M_ + tid + 256 * i) * NE_ + n;
            v[i] = logitsP[idx] + logitsP[CH + idx] + logitsP[2 * CH + idx] + logitsP[3 * CH + idx];
        }
        float mx = fmaxf(fmaxf(v[0], v[1]), fmaxf(v[2], v[3]));
#pragma unroll
        for (int off = 32; off; off >>= 1) mx = fmaxf(mx, __shfl_xor(mx, off));
        if ((tid & 63) == 0) red[tid >> 6] = mx;
        __syncthreads();
        mx = fmaxf(fmaxf(red[0], red[1]), fmaxf(red[2], red[3]));
        __syncthreads();
        float e[4], s = 0.f;
#pragma unroll
        for (int i = 0; i < 4; ++i) { e[i] = __expf(v[i] - mx); s += e[i]; }
#pragma unroll
        for (int off = 32; off; off >>= 1) s += __shfl_xor(s, off);
        if ((tid & 63) == 0) red[tid >> 6] = s;
        __syncthreads();
        s = red[0] + red[1] + red[2] + red[3];
        const float inv = 1.f / s;
#pragma unroll
        for (int i = 0; i < 4; ++i) O[tid + 256 * i] = f2bf(e[i] * inv);
    } else {
        const int idx4 = blockIdx.x - NE_;            // 0..255
        const int m = idx4 * 4 + (tid >> 6);
        const int lane = tid & 63;
        const size_t row = (size_t)b * M_ + m;
        const size_t i0 = row * NE_ + lane;
        const size_t i1 = i0 + 64;
        float a = logitsP[i0] + logitsP[CH + i0] + logitsP[2 * CH + i0] + logitsP[3 * CH + i0];
        float c = logitsP[i1] + logitsP[CH + i1] + logitsP[2 * CH + i1] + logitsP[3 * CH + i1];
        float mx = fmaxf(a, c);
#pragma unroll
        for (int off = 32; off; off >>= 1) mx = fmaxf(mx, __shfl_xor(mx, off));
        float e0 = __expf(a - mx), e1 = __expf(c - mx);
        float s = e0 + e1;
#pragma unroll
        for (int off = 32; off; off >>= 1) s += __shfl_xor(s, off);
        const float inv = 1.f / s;
        comb[row * NE_ + lane]      = f2bf(e0 * inv);
        comb[row * NE_ + lane + 64] = f2bf(e1 * inv);
    }
}

// ---------------------------------------------------------------------------
// Expert partials: part[c][b][n][d] = sum_{f in chunk c} slots[b][n][f]*w[n][f][d]
// Reads exp_w (2.15 GB) exactly once, float4-coalesced -> HBM-bound floor.
// ---------------------------------------------------------------------------
__global__ __launch_bounds__(256) void expert_partial_kernel(
    const float* __restrict__ slots, const float* __restrict__ exp_w,
    float* __restrict__ part)
{
    __shared__ float sl[4][512];
    const int n = blockIdx.x;
    const int c = blockIdx.y;
    const int f0 = c * 512;
    const int t = threadIdx.x;
    for (int i = t; i < 2048; i += 256) {
        const int b = i >> 9, f = i & 511;
        sl[b][f] = slots[((size_t)b * NE_ + n) * FF_ + f0 + f];
    }
    __syncthreads();
    const int d4 = t * 4;
    const float* wp = exp_w + ((size_t)n * FF_ + f0) * D_ + d4;
    f32x4 acc[4];
#pragma unroll
    for (int b = 0; b < 4; ++b)
#pragma unroll
        for (int j = 0; j < 4; ++j) acc[b][j] = 0.f;
#pragma unroll 4
    for (int f = 0; f < 512; ++f) {
        const float4 w4 = *(const float4*)wp;
        wp += D_;
#pragma unroll
        for (int b = 0; b < 4; ++b) {
            const float s = sl[b][f];
            acc[b][0] = fmaf(s, w4.x, acc[b][0]);
            acc[b][1] = fmaf(s, w4.y, acc[b][1]);
            acc[b][2] = fmaf(s, w4.z, acc[b][2]);
            acc[b][3] = fmaf(s, w4.w, acc[b][3]);
        }
    }
#pragma unroll
    for (int b = 0; b < 4; ++b)
        *(f32x4*)&part[(((size_t)c * 4 + b) * NE_ + n) * D_ + d4] = acc[b];
}

// ---------------------------------------------------------------------------
// Reduce 8 partials + exp_b, emit yT[b][d][n] bf16 (fused transpose).
// ---------------------------------------------------------------------------
__global__ __launch_bounds__(256) void reduce_yT_kernel(
    const float* __restrict__ part, const float* __restrict__ exp_b,
    u16* __restrict__ yT)
{
    __shared__ float tile[32][33];
    const int d0 = blockIdx.x * 32, n0 = blockIdx.y * 32, b = blockIdx.z;
    const int x = threadIdx.x & 31, y = threadIdx.x >> 5;
    for (int i = y; i < 32; i += 8) {
        const int n = n0 + i;
        float s = exp_b[(size_t)n * D_ + d0 + x];
#pragma unroll
        for (int c = 0; c < 8; ++c)
            s += part[(((size_t)c * 4 + b) * NE_ + n) * D_ + d0 + x];
        tile[i][x] = s;
    }
    __syncthreads();
    for (int i = y; i < 32; i += 8)
        yT[((size_t)b * D_ + d0 + i) * NE_ + n0 + x] = f2bf(tile[x][i]);
}

// ---------------------------------------------------------------------------
extern "C" void kernel_launch(void* const* d_in, const int* in_sizes, int n_in,
                              void* d_out, int out_size, void* d_ws, size_t ws_size,
                              hipStream_t stream)
{
    const float* tgt      = (const float*)d_in[0];
    const float* memry    = (const float*)d_in[1];
    const float* sa_in_w  = (const float*)d_in[2];
    const float* sa_in_b  = (const float*)d_in[3];
    const float* sa_out_w = (const float*)d_in[4];
    const float* sa_out_b = (const float*)d_in[5];
    const float* ca_in_w  = (const float*)d_in[6];
    const float* ca_in_b  = (const float*)d_in[7];
    const float* ca_out_w = (const float*)d_in[8];
    const float* ca_out_b = (const float*)d_in[9];
    const float* norm1_g  = (const float*)d_in[10];
    const float* norm1_b  = (const float*)d_in[11];
    const float* norm2_g  = (const float*)d_in[12];
    const float* norm2_b  = (const float*)d_in[13];
    const float* norm3_g  = (const float*)d_in[14];
    const float* norm3_b  = (const float*)d_in[15];
    const float* lin_w    = (const float*)d_in[16];
    const float* lin_b    = (const float*)d_in[17];
    const float* phi      = (const float*)d_in[18];
    const float* exp_w    = (const float*)d_in[19];
    const float* exp_b    = (const float*)d_in[20];

    float* ws = (float*)d_ws;
    u16*   qkv_bf  = (u16*)(ws);                 // [4096][3072] u16 (CA reuse)
    u16*   proj_bf = (u16*)(ws + 6291456);       // [4096][1024] u16
    float* logitsP = ws + 18874368;              // 4 x 524,288
    float* part    = ws + 20971520;              // 4,194,304
    u16*   h_bf    = (u16*)(ws + 25165824);      // [4096][4096]
    u16*   hT_bf   = (u16*)(ws + 33554432);      // [4][4096][1024]
    u16*   obuf_bf = (u16*)(ws + 41943040);      // [4096][1024]
    u16*   x1_bf   = (u16*)(ws + 44040192);
    u16*   x2_bf   = (u16*)(ws + 46137344);
    u16*   tgt_bf  = (u16*)(ws + 48234496);
    u16*   mem_bf  = (u16*)(ws + 50331648);
    u16*   dispT   = (u16*)(ws + 52428800);      // [4][128][1024]
    u16*   comb_bf = (u16*)(ws + 52690944);      // [4096][128]
    u16*   yT_bf   = (u16*)(ws + 52953088);      // [4][1024][128]
    float* slots   = ws + 53215232;              // 2,097,152
    u16*   w_sa_in = (u16*)(ws + 55312384);
    u16*   w_sa_out= (u16*)(ws + 56885248);
    u16*   w_ca_in = (u16*)(ws + 57409536);
    u16*   w_ca_out= (u16*)(ws + 58982400);
    u16*   w_lin   = (u16*)(ws + 59506688);
    u16*   phiT    = (u16*)(ws + 61603840);

    constexpr size_t CH = (size_t)B_ * M_ * NE_;

    // ---- bf16 conversions + phi transpose (single launch) ----
    cvt_multi_kernel<<<10752, 256, 0, stream>>>(
        tgt, tgt_bf, memry, mem_bf, sa_in_w, w_sa_in, sa_out_w, w_sa_out,
        ca_in_w, w_ca_in, ca_out_w, w_ca_out, lin_w, w_lin, phi, phiT);

    // ---- Self-attention ----
    gemm64_mfma<1, 0, 1, 0><<<dim3(24, 64, 1), 256, 0, stream>>>(
        tgt_bf, w_sa_in, sa_in_b, qkv_bf, nullptr, 1024, 3072, 1024, 1024, 0, 0, 0);
    flash_attn_kernel<<<dim3(8, 16, 4), 512, 0, stream>>>(
        qkv_bf, 3072, qkv_bf + 1024, 3072, qkv_bf + 2048, 3072, obuf_bf, S_);
    gemm64_mfma<1, 0, 1, 0><<<dim3(8, 64, 1), 256, 0, stream>>>(
        obuf_bf, w_sa_out, sa_out_b, proj_bf, nullptr, 1024, 1024, 1024, 1024, 0, 0, 0);
    resid_ln_kernel<0, 0><<<4096, 256, 0, stream>>>(tgt, proj_bf, norm1_g, norm1_b, x1_bf);

    // ---- Cross-attention ----
    u16* qca_bf = qkv_bf;
    u16* kvca_bf = qkv_bf + (size_t)4096 * 1024;
    gemm64_mfma<1, 0, 1, 0><<<dim3(8, 64, 1), 256, 0, stream>>>(
        x1_bf, w_ca_in, ca_in_b, qca_bf, nullptr, 1024, 1024, 1024, 1024, 0, 0, 0);
    gemm64_mfma<1, 0, 1, 0><<<dim3(16, 64, 1), 256, 0, stream>>>(
        mem_bf, w_ca_in + (size_t)1024 * 1024, ca_in_b + 1024,
        kvca_bf, nullptr, 1024, 2048, 1024, 1024, 0, 0, 0);
    flash_attn_kernel<<<dim3(8, 16, 4), 512, 0, stream>>>(
        qca_bf, 1024, kvca_bf, 2048, kvca_bf + 1024, 2048, obuf_bf, S_);
    gemm64_mfma<1, 0, 1, 0><<<dim3(8, 64, 1), 256, 0, stream>>>(
        obuf_bf, w_ca_out, ca_out_b, proj_bf, nullptr, 1024, 1024, 1024, 1024, 0, 0, 0);
    resid_ln_kernel<1, 0><<<4096, 256, 0, stream>>>(x1_bf, proj_bf, norm2_g, norm2_b, x2_bf);

    // ---- FF + SoftMoE ----
    gemm64_mfma<1, 1, 1, 1><<<dim3(32, 64, 1), 256, 0, stream>>>(
        x2_bf, w_lin, lin_b, h_bf, hT_bf, 1024, 4096, 1024, 1024, 0, 0, 0);
    // logits: split-K x4 (z = K-chunk of 1024)
    gemm64_mfma<0, 0, 0, 0><<<dim3(1, 64, 4), 256, 0, stream>>>(
        h_bf, phiT, nullptr, logitsP, nullptr, 1024, 128, 4096, 4096,
        1024, 1024, CH);
    moe_softmax_kernel<<<dim3(NE_ + 256, B_), 256, 0, stream>>>(logitsP, dispT, comb_bf);
    // slots = dispT @ hT (batched over B)
    gemm64_mfma<0, 0, 0, 0><<<dim3(32, 2, 4), 256, 0, stream>>>(
        dispT, hT_bf, nullptr, slots, nullptr, 1024, 4096, 1024, 1024,
        (size_t)NE_ * M_, (size_t)FF_ * M_, (size_t)NE_ * FF_);
    expert_partial_kernel<<<dim3(NE_, 8), 256, 0, stream>>>(slots, exp_w, part);
    reduce_yT_kernel<<<dim3(32, 4, 4), 256, 0, stream>>>(part, exp_b, yT_bf);
    // ff_out = combine @ y (batched over B), bf16 out
    gemm64_mfma<1, 0, 0, 0><<<dim3(8, 16, 4), 256, 0, stream>>>(
        comb_bf, yT_bf, nullptr, proj_bf, nullptr, 128, 1024, 128, 128,
        (size_t)M_ * NE_, (size_t)D_ * NE_, (size_t)M_ * D_);
    resid_ln_kernel<1, 1><<<4096, 256, 0, stream>>>(x2_bf, proj_bf, norm3_g, norm3_b,
                                                    (float*)d_out);
}